// Round 1
// baseline (2970.549 us; speedup 1.0000x reference)
//
#include <hip/hip_runtime.h>
#include <hip/hip_fp16.h>

// Problem constants (fixed by the harness' setup_inputs):
//   B=1000, L=50, D=128, NUM_ITEM=100000, NBIN=10, T=25500, n_edges=51000
#define D    128
#define L    50
#define G3   384          // 3*D
#define NBIN 10
#define RB   8            // sessions per GRU block
#define XT   32           // tokens per xps block
#define MT   20           // batch rows per final-matmul block

__device__ __forceinline__ float sigm(float x){ return 1.f/(1.f+__expf(-x)); }
__device__ __forceinline__ float tanh_fast(float x){
  float xx = fminf(fmaxf(x,-15.f),15.f);
  float e  = __expf(2.f*xx);
  return (e-1.f)/(e+1.f);
}

// ---------------- utility ----------------
__global__ void k_zero_f(float* __restrict__ p, long long n){
  long long i = (long long)blockIdx.x*blockDim.x + threadIdx.x;
  if (i < n) p[i] = 0.f;
}
__global__ void k_seti(int* __restrict__ p, int v, int n){
  int i = blockIdx.x*blockDim.x + threadIdx.x;
  if (i < n) p[i] = v;
}

// ---------------- xp tables: tab[v][g] = dot(bin_emb[v], Wih[g]) + bih[g] ----------------
__global__ void k_tables(const float* __restrict__ bin_emb,
                         const float* __restrict__ Wf, const float* __restrict__ bf,
                         const float* __restrict__ Wb, const float* __restrict__ bb,
                         float* __restrict__ tabf, float* __restrict__ tabb){
  int id = blockIdx.x*blockDim.x + threadIdx.x;
  if (id >= 2*NBIN*G3) return;
  int dir = id / (NBIN*G3);
  int r   = id % (NBIN*G3);
  int v = r / G3, g = r % G3;
  const float* W  = dir ? Wb : Wf;
  const float* bi = dir ? bb : bf;
  float acc = bi[g];
  for (int d = 0; d < D; ++d) acc += bin_emb[v*D+d]*W[g*D+d];
  (dir ? tabb : tabf)[v*G3+g] = acc;
}

// ---------------- GCN ----------------
__global__ void k_gcn_init(const float* __restrict__ item_emb, const int* __restrict__ items,
                           float* __restrict__ acc, float* __restrict__ x, int n){
  int i = blockIdx.x*256 + threadIdx.x;
  if (i >= n) return;
  int nn = i >> 7, d = i & (D-1);
  float v = item_emb[(size_t)items[nn]*D + d];
  acc[i] = v; x[i] = v;
}
__global__ void k_scatter(const float* __restrict__ x, float* __restrict__ xn,
                          const int* __restrict__ src, const int* __restrict__ dst,
                          const float* __restrict__ ew, int ne){
  int i = blockIdx.x*256 + threadIdx.x;
  if (i >= ne*D) return;
  int e = i >> 7, d = i & (D-1);
  atomicAdd(&xn[(size_t)dst[e]*D + d], x[(size_t)src[e]*D + d]*ew[e]);
}
__global__ void k_accum(float* __restrict__ acc, const float* __restrict__ xn, int n){
  int i = blockIdx.x*256 + threadIdx.x;
  if (i < n) acc[i] += xn[i];
}
__global__ void k_hgather(const float* __restrict__ acc, const int* __restrict__ idxmap,
                          float* __restrict__ htok, int Td){
  int i = blockIdx.x*256 + threadIdx.x;
  if (i >= Td) return;
  int t = i >> 7, d = i & (D-1);
  htok[i] = acc[(size_t)idxmap[t]*D + d]*0.25f;   // /(LAYER_NUM+1)
}

// ---------------- bidirectional GRU (forward dir=0, backward dir=1) ----------------
// One block owns RB sessions for all 50 steps. Whh staged ONCE in LDS as fp16
// (layout [(d>>2)*G3+g]*4+(d&3) -> half4 per (d4,g), <=4-way bank conflict).
__global__ __launch_bounds__(G3) void k_gru_fb(
    const float* __restrict__ Whh_f, const float* __restrict__ Whh_b,
    const float* __restrict__ bhh_f, const float* __restrict__ bhh_b,
    const float* __restrict__ tabf,  const float* __restrict__ tabb,
    const int*   __restrict__ bins,
    float* __restrict__ outf, float* __restrict__ outbrev){
  const int dir = blockIdx.y;
  const int b0  = blockIdx.x * RB;
  const float* Whh = dir ? Whh_b : Whh_f;
  const float* bhh = dir ? bhh_b : bhh_f;
  const float* tab = dir ? tabb  : tabf;
  float* outp = dir ? outbrev : outf;

  __shared__ __half wh[(D/4)*G3*4];   // 96 KB
  __shared__ float  xt[NBIN*G3];      // 15 KB
  __shared__ float4 hsv[RB][D/4];     // 4 KB
  __shared__ float  gh[RB][G3];       // 12 KB
  __shared__ int    binrow[RB][64];   // 2 KB

  for (int i = threadIdx.x; i < G3*D; i += G3){
    int g = i / D, d = i % D;
    wh[((d>>2)*G3 + g)*4 + (d&3)] = __float2half(Whh[i]);
  }
  for (int i = threadIdx.x; i < NBIN*G3; i += G3) xt[i] = tab[i];
  for (int i = threadIdx.x; i < RB*L; i += G3){
    int r = i / L, t = i % L;
    binrow[r][t] = bins[(b0+r)*L + (dir ? (L-1-t) : t)];
  }
  { float* hp = (float*)hsv;
    for (int i = threadIdx.x; i < RB*D; i += G3) hp[i] = 0.f; }
  __syncthreads();

  const int g = threadIdx.x;
  const float bh = bhh[g];
  for (int t = 0; t < L; ++t){
    float acc[RB];
#pragma unroll
    for (int r = 0; r < RB; ++r) acc[r] = 0.f;
#pragma unroll 4
    for (int d4 = 0; d4 < D/4; ++d4){
      const __half2* wp = (const __half2*)&wh[(d4*G3 + g)*4];
      float2 w01 = __half22float2(wp[0]);
      float2 w23 = __half22float2(wp[1]);
#pragma unroll
      for (int r = 0; r < RB; ++r){
        float4 h4 = hsv[r][d4];
        acc[r] += h4.x*w01.x + h4.y*w01.y + h4.z*w23.x + h4.w*w23.y;
      }
    }
#pragma unroll
    for (int r = 0; r < RB; ++r) gh[r][g] = acc[r] + bh;
    __syncthreads();
    float* hp = (float*)hsv;
    for (int idx = g; idx < RB*D; idx += G3){
      int r = idx >> 7, j = idx & (D-1);
      const float* xrow = &xt[binrow[r][t]*G3];
      float xr = xrow[j], xz = xrow[D+j], xn = xrow[2*D+j];
      float hr = gh[r][j], hz = gh[r][D+j], hn = gh[r][2*D+j];
      float rr = sigm(xr+hr);
      float zz = sigm(xz+hz);
      float nn = tanh_fast(xn + rr*hn);
      float hnew = (1.f-zz)*nn + zz*hp[idx];
      hp[idx] = hnew;
      outp[((size_t)(b0+r)*L + (dir ? (L-1-t) : t))*D + j] = hnew;
    }
    __syncthreads();
  }
}

// ---------------- e_hat + beta + c (fused), writes c into padded layout + token map ----------------
__global__ __launch_bounds__(256) void k_beta(
    const float* __restrict__ outf, const float* __restrict__ outbrev,
    const float* __restrict__ htok,
    const float* __restrict__ w1, const float* __restrict__ w2,
    const float* __restrict__ v3,
    const int* __restrict__ seg, const int* __restrict__ pos, int T,
    float* __restrict__ c_pad, int* __restrict__ tokmap){
  __shared__ float w2s[D][2*D+1];     // +1 pad: conflict-free column reads
  __shared__ float w1s[2*D];
  __shared__ float v3s[D];
  __shared__ float hfs[2][D], ehs[2][D];
  __shared__ float redA[4], redB[4];
  for (int i = threadIdx.x; i < D*2*D; i += 256) w2s[i/(2*D)][i%(2*D)] = w2[i];
  for (int i = threadIdx.x; i < 2*D;   i += 256) w1s[i] = w1[i];
  for (int i = threadIdx.x; i < D;     i += 256) v3s[i] = v3[i];
  __syncthreads();
  const int slot = threadIdx.x >> 7;
  const int j    = threadIdx.x & (D-1);
  const int wave = threadIdx.x >> 6;
  const int lane = threadIdx.x & 63;
  for (int t0 = blockIdx.x*2; t0 < T; t0 += gridDim.x*2){
    int t = t0 + slot;
    bool valid = (t < T);
    int sp = 0; float ef = 0.f, eb = 0.f, hfj = 0.f;
    if (valid){
      sp  = seg[t]*L + pos[t];
      ef  = outf[(size_t)sp*D + j];
      eb  = outbrev[(size_t)sp*D + j];
      hfj = htok[(size_t)t*D + j];
    }
    float p = ef*w1s[j] + eb*w1s[D+j];
#pragma unroll
    for (int off = 32; off >= 1; off >>= 1) p += __shfl_down(p, off);
    if (lane == 0) redA[wave] = p;
    __syncthreads();
    float gate = sigm(redA[slot*2] + redA[slot*2+1]);
    float ehj  = gate*ef + (1.f-gate)*eb;
    hfs[slot][j] = hfj;
    ehs[slot][j] = ehj;
    __syncthreads();
    float u = 0.f;
    for (int dd = 0; dd < D; ++dd){
      u += hfs[slot][dd]*w2s[j][dd];
      u += ehs[slot][dd]*w2s[j][D+dd];
    }
    u = tanh_fast(u);
    float pv = u * v3s[j];
#pragma unroll
    for (int off = 32; off >= 1; off >>= 1) pv += __shfl_down(pv, off);
    if (lane == 0) redB[wave] = pv;
    __syncthreads();
    float beta = redB[slot*2] + redB[slot*2+1];
    if (valid){
      c_pad[(size_t)sp*D + j] = beta * hfj;
      if (j == 0) tokmap[sp] = t;
    }
  }
}

// ---------------- z_long[b][j] = sum_l c_pad[b][l][j] ----------------
__global__ void k_zlong(const float* __restrict__ c_pad, float* __restrict__ zl, int Bn){
  int i = blockIdx.x*256 + threadIdx.x;
  if (i >= Bn*D) return;
  int b = i >> 7, j = i & (D-1);
  float s = 0.f;
  for (int l = 0; l < L; ++l) s += c_pad[((size_t)b*L + l)*D + j];
  zl[i] = s;
}

// ---------------- xps[t][g] = dot(c[t], Wih_s[g]) + bih_s[g]  (tokens only) ----------------
__global__ __launch_bounds__(G3) void k_xps(
    const float* __restrict__ c_pad, const int* __restrict__ seg,
    const int* __restrict__ pos, const float* __restrict__ Wih,
    const float* __restrict__ bih, int T, float* __restrict__ xps){
  int t0 = blockIdx.x * XT;
  __shared__ float cs[XT][D];
  int nt = min(XT, T - t0);
  for (int i = threadIdx.x; i < XT*D; i += G3){
    int tt = i >> 7, d = i & (D-1);
    float v = 0.f;
    if (tt < nt){
      int t = t0 + tt;
      v = c_pad[(size_t)(seg[t]*L + pos[t])*D + d];
    }
    cs[tt][d] = v;
  }
  __syncthreads();
  int gg = threadIdx.x;
  float acc[XT];
#pragma unroll
  for (int tt = 0; tt < XT; ++tt) acc[tt] = 0.f;
  for (int dc = 0; dc < D; dc += 16){
    float w[16];
#pragma unroll
    for (int k = 0; k < 16; ++k) w[k] = Wih[gg*D + dc + k];
#pragma unroll
    for (int tt = 0; tt < XT; ++tt){
#pragma unroll
      for (int k = 0; k < 16; ++k) acc[tt] += cs[tt][dc+k]*w[k];
    }
  }
  float bi = bih[gg];
  for (int tt = 0; tt < nt; ++tt) xps[(size_t)(t0+tt)*G3 + gg] = acc[tt] + bi;
}

// ---------------- short GRU over padded c, keep final h ----------------
__global__ __launch_bounds__(G3) void k_grus(
    const float* __restrict__ Whh, const float* __restrict__ bhh,
    const float* __restrict__ bih,
    const float* __restrict__ xps, const int* __restrict__ tokmap,
    float* __restrict__ z_short){
  const int b0 = blockIdx.x * RB;
  __shared__ __half wh[(D/4)*G3*4];
  __shared__ float4 hsv[RB][D/4];
  __shared__ float  gh[RB][G3];
  __shared__ int    maprow[RB][64];
  __shared__ float  bis[G3];

  for (int i = threadIdx.x; i < G3*D; i += G3){
    int g = i / D, d = i % D;
    wh[((d>>2)*G3 + g)*4 + (d&3)] = __float2half(Whh[i]);
  }
  bis[threadIdx.x] = bih[threadIdx.x];
  for (int i = threadIdx.x; i < RB*L; i += G3){
    int r = i / L, t = i % L;
    maprow[r][t] = tokmap[(b0+r)*L + t];
  }
  { float* hp = (float*)hsv;
    for (int i = threadIdx.x; i < RB*D; i += G3) hp[i] = 0.f; }
  __syncthreads();

  const int g = threadIdx.x;
  const float bh = bhh[g];
  for (int t = 0; t < L; ++t){
    float acc[RB];
#pragma unroll
    for (int r = 0; r < RB; ++r) acc[r] = 0.f;
#pragma unroll 4
    for (int d4 = 0; d4 < D/4; ++d4){
      const __half2* wp = (const __half2*)&wh[(d4*G3 + g)*4];
      float2 w01 = __half22float2(wp[0]);
      float2 w23 = __half22float2(wp[1]);
#pragma unroll
      for (int r = 0; r < RB; ++r){
        float4 h4 = hsv[r][d4];
        acc[r] += h4.x*w01.x + h4.y*w01.y + h4.z*w23.x + h4.w*w23.y;
      }
    }
#pragma unroll
    for (int r = 0; r < RB; ++r) gh[r][g] = acc[r] + bh;
    __syncthreads();
    float* hp = (float*)hsv;
    for (int idx = g; idx < RB*D; idx += G3){
      int r = idx >> 7, j = idx & (D-1);
      int tok = maprow[r][t];
      float xr, xz, xn;
      if (tok >= 0){
        const float* xrow = &xps[(size_t)tok*G3];
        xr = xrow[j]; xz = xrow[D+j]; xn = xrow[2*D+j];
      } else {
        xr = bis[j]; xz = bis[D+j]; xn = bis[2*D+j];
      }
      float hr = gh[r][j], hz = gh[r][D+j], hn = gh[r][2*D+j];
      float rr = sigm(xr+hr);
      float zz = sigm(xz+hz);
      float nn = tanh_fast(xn + rr*hn);
      float hnew = (1.f-zz)*nn + zz*hp[idx];
      hp[idx] = hnew;
    }
    __syncthreads();
  }
  float* hp = (float*)hsv;
  for (int idx = g; idx < RB*D; idx += G3)
    z_short[(size_t)b0*D + idx] = hp[idx];
}

// ---------------- final scalar gate ----------------
__global__ __launch_bounds__(D) void k_gate(
    const float* __restrict__ zl, const float* __restrict__ zs,
    const float* __restrict__ w3, const float* __restrict__ b3,
    float* __restrict__ zf){
  int b = blockIdx.x;
  int j = threadIdx.x;
  float a = zl[b*D+j], c = zs[b*D+j];
  float p = (a + c) * w3[j];
#pragma unroll
  for (int off = 32; off >= 1; off >>= 1) p += __shfl_down(p, off);
  __shared__ float red[2];
  if ((j & 63) == 0) red[j>>6] = p;
  __syncthreads();
  float f = sigm(red[0] + red[1] + b3[0]);
  zf[b*D+j] = f*a + (1.f-f)*c;
}

// ---------------- out[b][i] = dot(z_final[b], item_emb[i])  fp32 ----------------
__global__ __launch_bounds__(256) void k_final(
    const float* __restrict__ zf, const float* __restrict__ emb,
    float* __restrict__ out, int NI, int Bn){
  __shared__ float4 zt[MT][D/4];
  int m0 = blockIdx.y * MT;
  for (int i = threadIdx.x; i < MT*(D/4); i += 256){
    int m = i >> 5, k4 = i & 31;
    float4 z = make_float4(0.f,0.f,0.f,0.f);
    if (m0 + m < Bn) z = ((const float4*)zf)[(size_t)(m0+m)*(D/4) + k4];
    zt[m][k4] = z;
  }
  __syncthreads();
  int item0 = blockIdx.x*512 + threadIdx.x;
  int item1 = item0 + 256;
  bool v0 = item0 < NI, v1 = item1 < NI;
  float acc0[MT], acc1[MT];
#pragma unroll
  for (int m = 0; m < MT; ++m){ acc0[m] = 0.f; acc1[m] = 0.f; }
  const float4* e4 = (const float4*)emb;
  for (int k4 = 0; k4 < D/4; ++k4){
    float4 ea = v0 ? e4[(size_t)item0*(D/4) + k4] : make_float4(0.f,0.f,0.f,0.f);
    float4 eb = v1 ? e4[(size_t)item1*(D/4) + k4] : make_float4(0.f,0.f,0.f,0.f);
#pragma unroll
    for (int m = 0; m < MT; ++m){
      float4 z = zt[m][k4];
      acc0[m] += ea.x*z.x + ea.y*z.y + ea.z*z.z + ea.w*z.w;
      acc1[m] += eb.x*z.x + eb.y*z.y + eb.z*z.z + eb.w*z.w;
    }
  }
#pragma unroll
  for (int m = 0; m < MT; ++m){
    if (m0 + m >= Bn) break;
    if (v0) out[(size_t)(m0+m)*NI + item0] = acc0[m];
    if (v1) out[(size_t)(m0+m)*NI + item1] = acc1[m];
  }
}

extern "C" void kernel_launch(void* const* d_in, const int* in_sizes, int n_in,
                              void* d_out, int out_size, void* d_ws, size_t ws_size,
                              hipStream_t stream){
  const int*   items    = (const int*)d_in[0];
  const int*   edge     = (const int*)d_in[1];
  const float* ew       = (const float*)d_in[2];
  const int*   item2idx = (const int*)d_in[3];
  const int*   bins     = (const int*)d_in[4];
  const int*   seg      = (const int*)d_in[5];
  const int*   pos      = (const int*)d_in[6];
  const float* item_emb = (const float*)d_in[8];
  const float* bin_emb  = (const float*)d_in[9];
  const float* Wih_f = (const float*)d_in[10];
  const float* Whh_f = (const float*)d_in[11];
  const float* bih_f = (const float*)d_in[12];
  const float* bhh_f = (const float*)d_in[13];
  const float* Wih_b = (const float*)d_in[14];
  const float* Whh_b = (const float*)d_in[15];
  const float* bih_b = (const float*)d_in[16];
  const float* bhh_b = (const float*)d_in[17];
  const float* w1    = (const float*)d_in[18];
  const float* w2    = (const float*)d_in[19];
  const float* v3    = (const float*)d_in[20];
  const float* Wih_s = (const float*)d_in[21];
  const float* Whh_s = (const float*)d_in[22];
  const float* bih_s = (const float*)d_in[23];
  const float* bhh_s = (const float*)d_in[24];
  const float* w3    = (const float*)d_in[25];
  const float* b3    = (const float*)d_in[26];
  float* out = (float*)d_out;

  const int NN = in_sizes[0];          // 25500 graph nodes
  const int NE = in_sizes[2];          // 51000 edges
  const int T  = in_sizes[3];          // 25500 tokens
  const int B  = in_sizes[7];          // 1000 sessions
  const int NI = in_sizes[8] / D;      // 100000 items

  const size_t NG  = (size_t)NN * D;
  const size_t BLD = (size_t)B * L * D;

  // ws layout (floats). Peak ~118 MB. Regions A/B/C (GCN) are reused for
  // xps ([T][384] == exactly 3*NG here) after htok (in B) is consumed by k_beta.
  float* ws   = (float*)d_ws;
  float* accA = ws;
  float* xB   = ws + NG;
  float* xC   = ws + 2*NG;
  float* xps  = ws;                    // reuse A..C later
  float* outf = ws + 3*NG;
  float* outb = outf + BLD;
  float* cpad = outb + BLD;
  int*   tokmap = (int*)(cpad + BLD);
  float* tabf = (float*)(tokmap + (size_t)B*L);
  float* tabb = tabf + NBIN*G3;
  float* zl   = tabb + NBIN*G3;
  float* zs   = zl + (size_t)B*D;
  float* zfin = zs + (size_t)B*D;
  float* htok = xB;                    // token-level h_final after GCN

  // 1) xp tables for f/b GRUs (bins have only 10 distinct embeddings)
  hipLaunchKernelGGL(k_tables, dim3((2*NBIN*G3+255)/256), dim3(256), 0, stream,
                     bin_emb, Wih_f, bih_f, Wih_b, bih_b, tabf, tabb);
  // 2) GCN: acc = x = item_emb[items]; 3x {zero, scatter, accum}
  hipLaunchKernelGGL(k_gcn_init, dim3((unsigned)((NG+255)/256)), dim3(256), 0, stream,
                     item_emb, items, accA, xB, (int)NG);
  float* xc = xB; float* xn = xC;
  for (int layer = 0; layer < 3; ++layer){
    hipLaunchKernelGGL(k_zero_f, dim3((unsigned)((NG+255)/256)), dim3(256), 0, stream,
                       xn, (long long)NG);
    hipLaunchKernelGGL(k_scatter, dim3((unsigned)(((size_t)NE*D+255)/256)), dim3(256), 0, stream,
                       xc, xn, edge, edge+NE, ew, NE);
    hipLaunchKernelGGL(k_accum, dim3((unsigned)((NG+255)/256)), dim3(256), 0, stream,
                       accA, xn, (int)NG);
    float* tmp = xc; xc = xn; xn = tmp;
  }
  // after 3 swaps xn == xB (dead) -> htok target
  hipLaunchKernelGGL(k_hgather, dim3((unsigned)(((size_t)T*D+255)/256)), dim3(256), 0, stream,
                     accA, item2idx, htok, T*D);
  // 3) bidirectional GRU over bins (both directions in one grid)
  hipLaunchKernelGGL(k_gru_fb, dim3(B/RB, 2), dim3(G3), 0, stream,
                     Whh_f, Whh_b, bhh_f, bhh_b, tabf, tabb, bins, outf, outb);
  // 4) zero padded c + token map
  hipLaunchKernelGGL(k_zero_f, dim3((unsigned)((BLD+255)/256)), dim3(256), 0, stream,
                     cpad, (long long)BLD);
  hipLaunchKernelGGL(k_seti, dim3((B*L+255)/256), dim3(256), 0, stream, tokmap, -1, B*L);
  // 5) fused e_hat/beta/c
  hipLaunchKernelGGL(k_beta, dim3(256), dim3(256), 0, stream,
                     outf, outb, htok, w1, w2, v3, seg, pos, T, cpad, tokmap);
  // 6) z_long
  hipLaunchKernelGGL(k_zlong, dim3((B*D+255)/256), dim3(256), 0, stream, cpad, zl, B);
  // 7) xp for short GRU (tokens only) -- overwrites A..C (htok now dead)
  hipLaunchKernelGGL(k_xps, dim3((T+XT-1)/XT), dim3(G3), 0, stream,
                     cpad, seg, pos, Wih_s, bih_s, T, xps);
  // 8) short GRU -> z_short
  hipLaunchKernelGGL(k_grus, dim3(B/RB), dim3(G3), 0, stream,
                     Whh_s, bhh_s, bih_s, xps, tokmap, zs);
  // 9) scalar gate -> z_final
  hipLaunchKernelGGL(k_gate, dim3(B), dim3(D), 0, stream, zl, zs, w3, b3, zfin);
  // 10) out = z_final @ item_emb.T  (fp32 vector matmul)
  hipLaunchKernelGGL(k_final, dim3((NI+511)/512, (B+MT-1)/MT), dim3(256), 0, stream,
                     zfin, item_emb, out, NI, B);
}

// Round 2
// 1531.225 us; speedup vs baseline: 1.9400x; 1.9400x over previous
//
#include <hip/hip_runtime.h>
#include <hip/hip_fp16.h>

// Problem constants (fixed by the harness' setup_inputs):
//   B=1000, L=50, D=128, NUM_ITEM=100000, NBIN=10, T=25500, n_edges=51000
#define D    128
#define L    50
#define G3   384          // 3*D
#define NBIN 10
#define RB   8            // sessions per GRU block
#define XT   32           // tokens per xps block

// final-matmul (MFMA split-bf16) tile params
#define BM 256
#define BN 128
#define KC 64

typedef float f32x4 __attribute__((ext_vector_type(4)));
typedef short s16x8 __attribute__((ext_vector_type(8)));

__device__ __forceinline__ float sigm(float x){ return 1.f/(1.f+__expf(-x)); }
__device__ __forceinline__ float tanh_fast(float x){
  float xx = fminf(fmaxf(x,-15.f),15.f);
  float e  = __expf(2.f*xx);
  return (e-1.f)/(e+1.f);
}

// ---------------- utility ----------------
__global__ void k_zero_f(float* __restrict__ p, long long n){
  long long i = (long long)blockIdx.x*blockDim.x + threadIdx.x;
  if (i < n) p[i] = 0.f;
}
__global__ void k_seti(int* __restrict__ p, int v, int n){
  int i = blockIdx.x*blockDim.x + threadIdx.x;
  if (i < n) p[i] = v;
}

// ---------------- xp tables: tab[v][g] = dot(bin_emb[v], Wih[g]) + bih[g] ----------------
__global__ void k_tables(const float* __restrict__ bin_emb,
                         const float* __restrict__ Wf, const float* __restrict__ bf,
                         const float* __restrict__ Wb, const float* __restrict__ bb,
                         float* __restrict__ tabf, float* __restrict__ tabb){
  int id = blockIdx.x*blockDim.x + threadIdx.x;
  if (id >= 2*NBIN*G3) return;
  int dir = id / (NBIN*G3);
  int r   = id % (NBIN*G3);
  int v = r / G3, g = r % G3;
  const float* W  = dir ? Wb : Wf;
  const float* bi = dir ? bb : bf;
  float acc = bi[g];
  for (int d = 0; d < D; ++d) acc += bin_emb[v*D+d]*W[g*D+d];
  (dir ? tabb : tabf)[v*G3+g] = acc;
}

// ---------------- GCN ----------------
__global__ void k_gcn_init(const float* __restrict__ item_emb, const int* __restrict__ items,
                           float* __restrict__ acc, float* __restrict__ x, int n){
  int i = blockIdx.x*256 + threadIdx.x;
  if (i >= n) return;
  int nn = i >> 7, d = i & (D-1);
  float v = item_emb[(size_t)items[nn]*D + d];
  acc[i] = v; x[i] = v;
}
__global__ void k_scatter(const float* __restrict__ x, float* __restrict__ xn,
                          const int* __restrict__ src, const int* __restrict__ dst,
                          const float* __restrict__ ew, int ne){
  int i = blockIdx.x*256 + threadIdx.x;
  if (i >= ne*D) return;
  int e = i >> 7, d = i & (D-1);
  atomicAdd(&xn[(size_t)dst[e]*D + d], x[(size_t)src[e]*D + d]*ew[e]);
}
__global__ void k_accum(float* __restrict__ acc, const float* __restrict__ xn, int n){
  int i = blockIdx.x*256 + threadIdx.x;
  if (i < n) acc[i] += xn[i];
}
__global__ void k_hgather(const float* __restrict__ acc, const int* __restrict__ idxmap,
                          float* __restrict__ htok, int Td){
  int i = blockIdx.x*256 + threadIdx.x;
  if (i >= Td) return;
  int t = i >> 7, d = i & (D-1);
  htok[i] = acc[(size_t)idxmap[t]*D + d]*0.25f;   // /(LAYER_NUM+1)
}

// ---------------- bidirectional GRU (forward dir=0, backward dir=1) ----------------
__global__ __launch_bounds__(G3) void k_gru_fb(
    const float* __restrict__ Whh_f, const float* __restrict__ Whh_b,
    const float* __restrict__ bhh_f, const float* __restrict__ bhh_b,
    const float* __restrict__ tabf,  const float* __restrict__ tabb,
    const int*   __restrict__ bins,
    float* __restrict__ outf, float* __restrict__ outbrev){
  const int dir = blockIdx.y;
  const int b0  = blockIdx.x * RB;
  const float* Whh = dir ? Whh_b : Whh_f;
  const float* bhh = dir ? bhh_b : bhh_f;
  const float* tab = dir ? tabb  : tabf;
  float* outp = dir ? outbrev : outf;

  __shared__ __half wh[(D/4)*G3*4];   // 96 KB
  __shared__ float  xt[NBIN*G3];      // 15 KB
  __shared__ float4 hsv[RB][D/4];     // 4 KB
  __shared__ float  gh[RB][G3];       // 12 KB
  __shared__ int    binrow[RB][64];   // 2 KB

  for (int i = threadIdx.x; i < G3*D; i += G3){
    int g = i / D, d = i % D;
    wh[((d>>2)*G3 + g)*4 + (d&3)] = __float2half(Whh[i]);
  }
  for (int i = threadIdx.x; i < NBIN*G3; i += G3) xt[i] = tab[i];
  for (int i = threadIdx.x; i < RB*L; i += G3){
    int r = i / L, t = i % L;
    binrow[r][t] = bins[(b0+r)*L + (dir ? (L-1-t) : t)];
  }
  { float* hp = (float*)hsv;
    for (int i = threadIdx.x; i < RB*D; i += G3) hp[i] = 0.f; }
  __syncthreads();

  const int g = threadIdx.x;
  const float bh = bhh[g];
  for (int t = 0; t < L; ++t){
    float acc[RB];
#pragma unroll
    for (int r = 0; r < RB; ++r) acc[r] = 0.f;
#pragma unroll 4
    for (int d4 = 0; d4 < D/4; ++d4){
      const __half2* wp = (const __half2*)&wh[(d4*G3 + g)*4];
      float2 w01 = __half22float2(wp[0]);
      float2 w23 = __half22float2(wp[1]);
#pragma unroll
      for (int r = 0; r < RB; ++r){
        float4 h4 = hsv[r][d4];
        acc[r] += h4.x*w01.x + h4.y*w01.y + h4.z*w23.x + h4.w*w23.y;
      }
    }
#pragma unroll
    for (int r = 0; r < RB; ++r) gh[r][g] = acc[r] + bh;
    __syncthreads();
    float* hp = (float*)hsv;
    for (int idx = g; idx < RB*D; idx += G3){
      int r = idx >> 7, j = idx & (D-1);
      const float* xrow = &xt[binrow[r][t]*G3];
      float xr = xrow[j], xz = xrow[D+j], xn = xrow[2*D+j];
      float hr = gh[r][j], hz = gh[r][D+j], hn = gh[r][2*D+j];
      float rr = sigm(xr+hr);
      float zz = sigm(xz+hz);
      float nn = tanh_fast(xn + rr*hn);
      float hnew = (1.f-zz)*nn + zz*hp[idx];
      hp[idx] = hnew;
      outp[((size_t)(b0+r)*L + (dir ? (L-1-t) : t))*D + j] = hnew;
    }
    __syncthreads();
  }
}

// ---------------- e_hat + beta + c (fused) ----------------
__global__ __launch_bounds__(256) void k_beta(
    const float* __restrict__ outf, const float* __restrict__ outbrev,
    const float* __restrict__ htok,
    const float* __restrict__ w1, const float* __restrict__ w2,
    const float* __restrict__ v3,
    const int* __restrict__ seg, const int* __restrict__ pos, int T,
    float* __restrict__ c_pad, int* __restrict__ tokmap){
  __shared__ float w2s[D][2*D+1];     // +1 pad: conflict-free column reads
  __shared__ float w1s[2*D];
  __shared__ float v3s[D];
  __shared__ float hfs[2][D], ehs[2][D];
  __shared__ float redA[4], redB[4];
  for (int i = threadIdx.x; i < D*2*D; i += 256) w2s[i/(2*D)][i%(2*D)] = w2[i];
  for (int i = threadIdx.x; i < 2*D;   i += 256) w1s[i] = w1[i];
  for (int i = threadIdx.x; i < D;     i += 256) v3s[i] = v3[i];
  __syncthreads();
  const int slot = threadIdx.x >> 7;
  const int j    = threadIdx.x & (D-1);
  const int wave = threadIdx.x >> 6;
  const int lane = threadIdx.x & 63;
  for (int t0 = blockIdx.x*2; t0 < T; t0 += gridDim.x*2){
    int t = t0 + slot;
    bool valid = (t < T);
    int sp = 0; float ef = 0.f, eb = 0.f, hfj = 0.f;
    if (valid){
      sp  = seg[t]*L + pos[t];
      ef  = outf[(size_t)sp*D + j];
      eb  = outbrev[(size_t)sp*D + j];
      hfj = htok[(size_t)t*D + j];
    }
    float p = ef*w1s[j] + eb*w1s[D+j];
#pragma unroll
    for (int off = 32; off >= 1; off >>= 1) p += __shfl_down(p, off);
    if (lane == 0) redA[wave] = p;
    __syncthreads();
    float gate = sigm(redA[slot*2] + redA[slot*2+1]);
    float ehj  = gate*ef + (1.f-gate)*eb;
    hfs[slot][j] = hfj;
    ehs[slot][j] = ehj;
    __syncthreads();
    float u = 0.f;
    for (int dd = 0; dd < D; ++dd){
      u += hfs[slot][dd]*w2s[j][dd];
      u += ehs[slot][dd]*w2s[j][D+dd];
    }
    u = tanh_fast(u);
    float pv = u * v3s[j];
#pragma unroll
    for (int off = 32; off >= 1; off >>= 1) pv += __shfl_down(pv, off);
    if (lane == 0) redB[wave] = pv;
    __syncthreads();
    float beta = redB[slot*2] + redB[slot*2+1];
    if (valid){
      c_pad[(size_t)sp*D + j] = beta * hfj;
      if (j == 0) tokmap[sp] = t;
    }
  }
}

// ---------------- z_long ----------------
__global__ void k_zlong(const float* __restrict__ c_pad, float* __restrict__ zl, int Bn){
  int i = blockIdx.x*256 + threadIdx.x;
  if (i >= Bn*D) return;
  int b = i >> 7, j = i & (D-1);
  float s = 0.f;
  for (int l = 0; l < L; ++l) s += c_pad[((size_t)b*L + l)*D + j];
  zl[i] = s;
}

// ---------------- xps[t][g] = dot(c[t], Wih_s[g]) + bih_s[g] ----------------
__global__ __launch_bounds__(G3) void k_xps(
    const float* __restrict__ c_pad, const int* __restrict__ seg,
    const int* __restrict__ pos, const float* __restrict__ Wih,
    const float* __restrict__ bih, int T, float* __restrict__ xps){
  int t0 = blockIdx.x * XT;
  __shared__ float cs[XT][D];
  int nt = min(XT, T - t0);
  for (int i = threadIdx.x; i < XT*D; i += G3){
    int tt = i >> 7, d = i & (D-1);
    float v = 0.f;
    if (tt < nt){
      int t = t0 + tt;
      v = c_pad[(size_t)(seg[t]*L + pos[t])*D + d];
    }
    cs[tt][d] = v;
  }
  __syncthreads();
  int gg = threadIdx.x;
  float acc[XT];
#pragma unroll
  for (int tt = 0; tt < XT; ++tt) acc[tt] = 0.f;
  for (int dc = 0; dc < D; dc += 16){
    float w[16];
#pragma unroll
    for (int k = 0; k < 16; ++k) w[k] = Wih[gg*D + dc + k];
#pragma unroll
    for (int tt = 0; tt < XT; ++tt){
#pragma unroll
      for (int k = 0; k < 16; ++k) acc[tt] += cs[tt][dc+k]*w[k];
    }
  }
  float bi = bih[gg];
  for (int tt = 0; tt < nt; ++tt) xps[(size_t)(t0+tt)*G3 + gg] = acc[tt] + bi;
}

// ---------------- short GRU over padded c, keep final h ----------------
__global__ __launch_bounds__(G3) void k_grus(
    const float* __restrict__ Whh, const float* __restrict__ bhh,
    const float* __restrict__ bih,
    const float* __restrict__ xps, const int* __restrict__ tokmap,
    float* __restrict__ z_short){
  const int b0 = blockIdx.x * RB;
  __shared__ __half wh[(D/4)*G3*4];
  __shared__ float4 hsv[RB][D/4];
  __shared__ float  gh[RB][G3];
  __shared__ int    maprow[RB][64];
  __shared__ float  bis[G3];

  for (int i = threadIdx.x; i < G3*D; i += G3){
    int g = i / D, d = i % D;
    wh[((d>>2)*G3 + g)*4 + (d&3)] = __float2half(Whh[i]);
  }
  bis[threadIdx.x] = bih[threadIdx.x];
  for (int i = threadIdx.x; i < RB*L; i += G3){
    int r = i / L, t = i % L;
    maprow[r][t] = tokmap[(b0+r)*L + t];
  }
  { float* hp = (float*)hsv;
    for (int i = threadIdx.x; i < RB*D; i += G3) hp[i] = 0.f; }
  __syncthreads();

  const int g = threadIdx.x;
  const float bh = bhh[g];
  for (int t = 0; t < L; ++t){
    float acc[RB];
#pragma unroll
    for (int r = 0; r < RB; ++r) acc[r] = 0.f;
#pragma unroll 4
    for (int d4 = 0; d4 < D/4; ++d4){
      const __half2* wp = (const __half2*)&wh[(d4*G3 + g)*4];
      float2 w01 = __half22float2(wp[0]);
      float2 w23 = __half22float2(wp[1]);
#pragma unroll
      for (int r = 0; r < RB; ++r){
        float4 h4 = hsv[r][d4];
        acc[r] += h4.x*w01.x + h4.y*w01.y + h4.z*w23.x + h4.w*w23.y;
      }
    }
#pragma unroll
    for (int r = 0; r < RB; ++r) gh[r][g] = acc[r] + bh;
    __syncthreads();
    float* hp = (float*)hsv;
    for (int idx = g; idx < RB*D; idx += G3){
      int r = idx >> 7, j = idx & (D-1);
      int tok = maprow[r][t];
      float xr, xz, xn;
      if (tok >= 0){
        const float* xrow = &xps[(size_t)tok*G3];
        xr = xrow[j]; xz = xrow[D+j]; xn = xrow[2*D+j];
      } else {
        xr = bis[j]; xz = bis[D+j]; xn = bis[2*D+j];
      }
      float hr = gh[r][j], hz = gh[r][D+j], hn = gh[r][2*D+j];
      float rr = sigm(xr+hr);
      float zz = sigm(xz+hz);
      float nn = tanh_fast(xn + rr*hn);
      float hnew = (1.f-zz)*nn + zz*hp[idx];
      hp[idx] = hnew;
    }
    __syncthreads();
  }
  float* hp = (float*)hsv;
  for (int idx = g; idx < RB*D; idx += G3)
    z_short[(size_t)b0*D + idx] = hp[idx];
}

// ---------------- final scalar gate ----------------
__global__ __launch_bounds__(D) void k_gate(
    const float* __restrict__ zl, const float* __restrict__ zs,
    const float* __restrict__ w3, const float* __restrict__ b3,
    float* __restrict__ zf){
  int b = blockIdx.x;
  int j = threadIdx.x;
  float a = zl[b*D+j], c = zs[b*D+j];
  float p = (a + c) * w3[j];
#pragma unroll
  for (int off = 32; off >= 1; off >>= 1) p += __shfl_down(p, off);
  __shared__ float red[2];
  if ((j & 63) == 0) red[j>>6] = p;
  __syncthreads();
  float f = sigm(red[0] + red[1] + b3[0]);
  zf[b*D+j] = f*a + (1.f-f)*c;
}

// ---------------- out = z_final @ item_emb.T  via split-bf16 MFMA ----------------
// C = zhi*ehi + zhi*elo + zlo*ehi  (lo*lo dropped, ~2^-16 relative)
// LDS: XOR-swizzled (slot ^= row&7) rows of 128B -> ds_read_b128 at bank floor.
#define SPLIT1(x, hu, lu) { unsigned u_ = __float_as_uint(x); hu = u_ >> 16; \
  float hf_ = __uint_as_float(u_ & 0xffff0000u); float lf_ = (x) - hf_; \
  lu = __float_as_uint(lf_) >> 16; }

__global__ __launch_bounds__(512) void k_fmm(
    const float* __restrict__ zfin, const float* __restrict__ emb,
    float* __restrict__ out, int NI, int Bsz){
  __shared__ unsigned short Ah[BM*KC], Al[BM*KC], Bh[BN*KC], Bl[BN*KC];  // 96 KB

  // bijective XCD-chunked remap (m204): logical-consecutive blocks share an XCD
  int nwg = gridDim.x;
  int hw  = blockIdx.x;
  int q = nwg >> 3, r = nwg & 7;
  int xcd = hw & 7, idx = hw >> 3;
  int logical = (xcd < r ? xcd*(q+1) : r*(q+1) + (xcd-r)*q) + idx;
  int ntile = logical >> 2;       // 4 M-tiles per N-tile
  int mtile = logical & 3;
  int m0 = mtile*BM;
  int n0 = ntile*BN;

  const int t    = threadIdx.x;
  const int lane = t & 63;
  const int wid  = t >> 6;
  const int wm   = wid >> 1, wn = wid & 1;   // 4 x 2 wave grid, 64x64 each
  const int l15  = lane & 15, lk = lane >> 4;

  f32x4 acc[4][4];
#pragma unroll
  for (int i = 0; i < 4; ++i)
#pragma unroll
    for (int j = 0; j < 4; ++j){ f32x4 z4 = {0.f,0.f,0.f,0.f}; acc[i][j] = z4; }

  const int rbase = t >> 3;        // 0..63
  const int c8    = t & 7;         // 8B-slot within 64-col chunk

  for (int kc = 0; kc < 2; ++kc){
    // ---- stage A (z rows), 4 passes x 64 rows, convert fp32 -> hi/lo bf16
#pragma unroll
    for (int p = 0; p < 4; ++p){
      int row = p*64 + rbase;
      int m = m0 + row;
      float4 x0 = make_float4(0.f,0.f,0.f,0.f), x1 = x0;
      if (m < Bsz){
        const float4* src = (const float4*)&zfin[(size_t)m*D + kc*KC + c8*8];
        x0 = src[0]; x1 = src[1];
      }
      unsigned h0,h1,h2,h3,h4,h5,h6,h7, l0,l1,l2,l3,l4,l5,l6,l7;
      SPLIT1(x0.x,h0,l0) SPLIT1(x0.y,h1,l1) SPLIT1(x0.z,h2,l2) SPLIT1(x0.w,h3,l3)
      SPLIT1(x1.x,h4,l4) SPLIT1(x1.y,h5,l5) SPLIT1(x1.z,h6,l6) SPLIT1(x1.w,h7,l7)
      int4 hv = make_int4((int)(h0|(h1<<16)),(int)(h2|(h3<<16)),(int)(h4|(h5<<16)),(int)(h6|(h7<<16)));
      int4 lv = make_int4((int)(l0|(l1<<16)),(int)(l2|(l3<<16)),(int)(l4|(l5<<16)),(int)(l6|(l7<<16)));
      int byte = row*128 + ((c8 ^ (row&7))<<4);
      *(int4*)((char*)Ah + byte) = hv;
      *(int4*)((char*)Al + byte) = lv;
    }
    // ---- stage B (emb rows), 2 passes x 64 rows
#pragma unroll
    for (int p = 0; p < 2; ++p){
      int row = p*64 + rbase;
      int item = n0 + row;
      float4 x0 = make_float4(0.f,0.f,0.f,0.f), x1 = x0;
      if (item < NI){
        const float4* src = (const float4*)&emb[(size_t)item*D + kc*KC + c8*8];
        x0 = src[0]; x1 = src[1];
      }
      unsigned h0,h1,h2,h3,h4,h5,h6,h7, l0,l1,l2,l3,l4,l5,l6,l7;
      SPLIT1(x0.x,h0,l0) SPLIT1(x0.y,h1,l1) SPLIT1(x0.z,h2,l2) SPLIT1(x0.w,h3,l3)
      SPLIT1(x1.x,h4,l4) SPLIT1(x1.y,h5,l5) SPLIT1(x1.z,h6,l6) SPLIT1(x1.w,h7,l7)
      int4 hv = make_int4((int)(h0|(h1<<16)),(int)(h2|(h3<<16)),(int)(h4|(h5<<16)),(int)(h6|(h7<<16)));
      int4 lv = make_int4((int)(l0|(l1<<16)),(int)(l2|(l3<<16)),(int)(l4|(l5<<16)),(int)(l6|(l7<<16)));
      int byte = row*128 + ((c8 ^ (row&7))<<4);
      *(int4*)((char*)Bh + byte) = hv;
      *(int4*)((char*)Bl + byte) = lv;
    }
    __syncthreads();

    // ---- compute: 2 k-steps of 32 within this 64-chunk
#pragma unroll
    for (int ks = 0; ks < 2; ++ks){
      int slotb = ks*4 + lk;
      s16x8 ah[4], al4[4], bh4[4], bl4[4];
#pragma unroll
      for (int mf = 0; mf < 4; ++mf){
        int row = wm*64 + mf*16 + l15;
        int byte = row*128 + ((slotb ^ (row&7))<<4);
        ah[mf]  = *(const s16x8*)((const char*)Ah + byte);
        al4[mf] = *(const s16x8*)((const char*)Al + byte);
      }
#pragma unroll
      for (int nf = 0; nf < 4; ++nf){
        int row = wn*64 + nf*16 + l15;
        int byte = row*128 + ((slotb ^ (row&7))<<4);
        bh4[nf] = *(const s16x8*)((const char*)Bh + byte);
        bl4[nf] = *(const s16x8*)((const char*)Bl + byte);
      }
#pragma unroll
      for (int mf = 0; mf < 4; ++mf)
#pragma unroll
        for (int nf = 0; nf < 4; ++nf){
          acc[mf][nf] = __builtin_amdgcn_mfma_f32_16x16x32_bf16(ah[mf],  bh4[nf], acc[mf][nf], 0,0,0);
          acc[mf][nf] = __builtin_amdgcn_mfma_f32_16x16x32_bf16(ah[mf],  bl4[nf], acc[mf][nf], 0,0,0);
          acc[mf][nf] = __builtin_amdgcn_mfma_f32_16x16x32_bf16(al4[mf], bh4[nf], acc[mf][nf], 0,0,0);
        }
    }
    __syncthreads();
  }

  // ---- store: C row = (lane>>4)*4 + q, col = lane&15 (m89-verified layout)
#pragma unroll
  for (int mf = 0; mf < 4; ++mf){
    int rowb = m0 + wm*64 + mf*16 + lk*4;
#pragma unroll
    for (int nf = 0; nf < 4; ++nf){
      int col = n0 + wn*64 + nf*16 + l15;
      if (col < NI){
#pragma unroll
        for (int qq = 0; qq < 4; ++qq){
          int rr = rowb + qq;
          if (rr < Bsz) out[(size_t)rr*NI + col] = acc[mf][nf][qq];
        }
      }
    }
  }
}

extern "C" void kernel_launch(void* const* d_in, const int* in_sizes, int n_in,
                              void* d_out, int out_size, void* d_ws, size_t ws_size,
                              hipStream_t stream){
  const int*   items    = (const int*)d_in[0];
  const int*   edge     = (const int*)d_in[1];
  const float* ew       = (const float*)d_in[2];
  const int*   item2idx = (const int*)d_in[3];
  const int*   bins     = (const int*)d_in[4];
  const int*   seg      = (const int*)d_in[5];
  const int*   pos      = (const int*)d_in[6];
  const float* item_emb = (const float*)d_in[8];
  const float* bin_emb  = (const float*)d_in[9];
  const float* Wih_f = (const float*)d_in[10];
  const float* Whh_f = (const float*)d_in[11];
  const float* bih_f = (const float*)d_in[12];
  const float* bhh_f = (const float*)d_in[13];
  const float* Wih_b = (const float*)d_in[14];
  const float* Whh_b = (const float*)d_in[15];
  const float* bih_b = (const float*)d_in[16];
  const float* bhh_b = (const float*)d_in[17];
  const float* w1    = (const float*)d_in[18];
  const float* w2    = (const float*)d_in[19];
  const float* v3    = (const float*)d_in[20];
  const float* Wih_s = (const float*)d_in[21];
  const float* Whh_s = (const float*)d_in[22];
  const float* bih_s = (const float*)d_in[23];
  const float* bhh_s = (const float*)d_in[24];
  const float* w3    = (const float*)d_in[25];
  const float* b3    = (const float*)d_in[26];
  float* out = (float*)d_out;

  const int NN = in_sizes[0];          // 25500 graph nodes
  const int NE = in_sizes[2];          // 51000 edges
  const int T  = in_sizes[3];          // 25500 tokens
  const int B  = in_sizes[7];          // 1000 sessions
  const int NI = in_sizes[8] / D;      // 100000 items

  const size_t NG  = (size_t)NN * D;
  const size_t BLD = (size_t)B * L * D;

  float* ws   = (float*)d_ws;
  float* accA = ws;
  float* xB   = ws + NG;
  float* xC   = ws + 2*NG;
  float* xps  = ws;                    // reuse A..C later
  float* outf = ws + 3*NG;
  float* outb = outf + BLD;
  float* cpad = outb + BLD;
  int*   tokmap = (int*)(cpad + BLD);
  float* tabf = (float*)(tokmap + (size_t)B*L);
  float* tabb = tabf + NBIN*G3;
  float* zl   = tabb + NBIN*G3;
  float* zs   = zl + (size_t)B*D;
  float* zfin = zs + (size_t)B*D;
  float* htok = xB;                    // token-level h_final after GCN

  // 1) xp tables
  hipLaunchKernelGGL(k_tables, dim3((2*NBIN*G3+255)/256), dim3(256), 0, stream,
                     bin_emb, Wih_f, bih_f, Wih_b, bih_b, tabf, tabb);
  // 2) GCN
  hipLaunchKernelGGL(k_gcn_init, dim3((unsigned)((NG+255)/256)), dim3(256), 0, stream,
                     item_emb, items, accA, xB, (int)NG);
  float* xc = xB; float* xn = xC;
  for (int layer = 0; layer < 3; ++layer){
    hipLaunchKernelGGL(k_zero_f, dim3((unsigned)((NG+255)/256)), dim3(256), 0, stream,
                       xn, (long long)NG);
    hipLaunchKernelGGL(k_scatter, dim3((unsigned)(((size_t)NE*D+255)/256)), dim3(256), 0, stream,
                       xc, xn, edge, edge+NE, ew, NE);
    hipLaunchKernelGGL(k_accum, dim3((unsigned)((NG+255)/256)), dim3(256), 0, stream,
                       accA, xn, (int)NG);
    float* tmp = xc; xc = xn; xn = tmp;
  }
  hipLaunchKernelGGL(k_hgather, dim3((unsigned)(((size_t)T*D+255)/256)), dim3(256), 0, stream,
                     accA, item2idx, htok, T*D);
  // 3) bidirectional GRU
  hipLaunchKernelGGL(k_gru_fb, dim3(B/RB, 2), dim3(G3), 0, stream,
                     Whh_f, Whh_b, bhh_f, bhh_b, tabf, tabb, bins, outf, outb);
  // 4) zero padded c + token map
  hipLaunchKernelGGL(k_zero_f, dim3((unsigned)((BLD+255)/256)), dim3(256), 0, stream,
                     cpad, (long long)BLD);
  hipLaunchKernelGGL(k_seti, dim3((B*L+255)/256), dim3(256), 0, stream, tokmap, -1, B*L);
  // 5) fused e_hat/beta/c
  hipLaunchKernelGGL(k_beta, dim3(256), dim3(256), 0, stream,
                     outf, outb, htok, w1, w2, v3, seg, pos, T, cpad, tokmap);
  // 6) z_long
  hipLaunchKernelGGL(k_zlong, dim3((B*D+255)/256), dim3(256), 0, stream, cpad, zl, B);
  // 7) xps for short GRU
  hipLaunchKernelGGL(k_xps, dim3((T+XT-1)/XT), dim3(G3), 0, stream,
                     cpad, seg, pos, Wih_s, bih_s, T, xps);
  // 8) short GRU
  hipLaunchKernelGGL(k_grus, dim3(B/RB), dim3(G3), 0, stream,
                     Whh_s, bhh_s, bih_s, xps, tokmap, zs);
  // 9) scalar gate
  hipLaunchKernelGGL(k_gate, dim3(B), dim3(D), 0, stream, zl, zs, w3, b3, zfin);
  // 10) out = z_final @ item_emb.T  (split-bf16 MFMA GEMM)
  {
    int mtiles = (B + BM - 1)/BM;          // 4
    int ntiles = (NI + BN - 1)/BN;         // 782
    hipLaunchKernelGGL(k_fmm, dim3(mtiles*ntiles), dim3(512), 0, stream,
                       zfin, item_emb, out, NI, B);
  }
}

// Round 3
// 755.182 us; speedup vs baseline: 3.9336x; 2.0276x over previous
//
#include <hip/hip_runtime.h>
#include <hip/hip_fp16.h>

// Problem constants (fixed by the harness' setup_inputs):
//   B=1000, L=50, D=128, NUM_ITEM=100000, NBIN=10, T=25500, n_edges=51000
#define D    128
#define L    50
#define G3   384          // 3*D
#define NBIN 10
#define XT   32           // tokens per xps block
#define RBF  8            // sessions per block, bidirectional GRU
#define RBS  4            // sessions per block, short GRU
#define GW   48           // gates per wave (8 waves x 48 = 384)

// final-matmul (MFMA split-bf16) tile params
#define BM 256
#define BN 128
#define KC 64

typedef float f32x4 __attribute__((ext_vector_type(4)));
typedef short s16x8 __attribute__((ext_vector_type(8)));

#define MFMA_B16(a,b,c) __builtin_amdgcn_mfma_f32_16x16x32_bf16(a,b,c,0,0,0)

__device__ __forceinline__ float sigm(float x){ return 1.f/(1.f+__expf(-x)); }
__device__ __forceinline__ float tanh_fast(float x){
  float xx = fminf(fmaxf(x,-15.f),15.f);
  float e  = __expf(2.f*xx);
  return (e-1.f)/(e+1.f);
}

// split fp32 -> (hi bf16, lo bf16): x ~= hi + lo to ~2^-17 rel
#define SPLIT1(x, hu, lu) { unsigned u_ = __float_as_uint(x); hu = u_ >> 16; \
  float hf_ = __uint_as_float(u_ & 0xffff0000u); float lf_ = (x) - hf_; \
  lu = __float_as_uint(lf_) >> 16; }

__device__ __forceinline__ void split8(float4 a, float4 b, s16x8& hi, s16x8& lo){
  float v[8] = {a.x,a.y,a.z,a.w,b.x,b.y,b.z,b.w};
  s16x8 h, l;
#pragma unroll
  for (int i=0;i<8;++i){
    unsigned hu, lu;
    SPLIT1(v[i], hu, lu)
    h[i] = (short)hu; l[i] = (short)lu;
  }
  hi = h; lo = l;
}

// ---------------- utility ----------------
__global__ void k_zero_f(float* __restrict__ p, long long n){
  long long i = (long long)blockIdx.x*blockDim.x + threadIdx.x;
  if (i < n) p[i] = 0.f;
}
__global__ void k_seti(int* __restrict__ p, int v, int n){
  int i = blockIdx.x*blockDim.x + threadIdx.x;
  if (i < n) p[i] = v;
}

// ---------------- xp tables: tab[v][g] = dot(bin_emb[v], Wih[g]) + bih[g] ----------------
__global__ void k_tables(const float* __restrict__ bin_emb,
                         const float* __restrict__ Wf, const float* __restrict__ bf,
                         const float* __restrict__ Wb, const float* __restrict__ bb,
                         float* __restrict__ tabf, float* __restrict__ tabb){
  int id = blockIdx.x*blockDim.x + threadIdx.x;
  if (id >= 2*NBIN*G3) return;
  int dir = id / (NBIN*G3);
  int r   = id % (NBIN*G3);
  int v = r / G3, g = r % G3;
  const float* W  = dir ? Wb : Wf;
  const float* bi = dir ? bb : bf;
  float acc = bi[g];
  for (int d = 0; d < D; ++d) acc += bin_emb[v*D+d]*W[g*D+d];
  (dir ? tabb : tabf)[v*G3+g] = acc;
}

// ---------------- GCN ----------------
__global__ void k_gcn_init(const float* __restrict__ item_emb, const int* __restrict__ items,
                           float* __restrict__ acc, float* __restrict__ x, int n){
  int i = blockIdx.x*256 + threadIdx.x;
  if (i >= n) return;
  int nn = i >> 7, d = i & (D-1);
  float v = item_emb[(size_t)items[nn]*D + d];
  acc[i] = v; x[i] = v;
}
__global__ void k_scatter(const float* __restrict__ x, float* __restrict__ xn,
                          const int* __restrict__ src, const int* __restrict__ dst,
                          const float* __restrict__ ew, int ne){
  int i = blockIdx.x*256 + threadIdx.x;
  if (i >= ne*D) return;
  int e = i >> 7, d = i & (D-1);
  atomicAdd(&xn[(size_t)dst[e]*D + d], x[(size_t)src[e]*D + d]*ew[e]);
}
__global__ void k_accum(float* __restrict__ acc, const float* __restrict__ xn, int n){
  int i = blockIdx.x*256 + threadIdx.x;
  if (i < n) acc[i] += xn[i];
}
__global__ void k_hgather(const float* __restrict__ acc, const int* __restrict__ idxmap,
                          float* __restrict__ htok, int Td){
  int i = blockIdx.x*256 + threadIdx.x;
  if (i >= Td) return;
  int t = i >> 7, d = i & (D-1);
  htok[i] = acc[(size_t)idxmap[t]*D + d]*0.25f;   // /(LAYER_NUM+1)
}

// ============ MFMA GRU core idea ============
// Recurrent matmul gh[384][S] = Whh @ h^T via mfma_f32_16x16x32_bf16.
// A = Whh (gates=M), held in REGISTERS as split-bf16 fragments (loop-invariant).
// B = h (sessions=N<=16), stored in LDS as hi/lo bf16, XOR-swizzled 16B slots.
// C layout: row(gate-in-tile) = lk*4+q, col(sess) = lane&15 (m89-verified).
// gh staged through stride-17 LDS; elementwise phase updates h hi/lo in place.

// ---------------- bidirectional GRU (fwd dir=0, bwd dir=1), RBF=8 sessions/block ----------------
__global__ __launch_bounds__(512) void k_gru_fb(
    const float* __restrict__ Whh_f, const float* __restrict__ Whh_b,
    const float* __restrict__ bhh_f, const float* __restrict__ bhh_b,
    const float* __restrict__ tabf,  const float* __restrict__ tabb,
    const int*   __restrict__ bins,
    float* __restrict__ outf, float* __restrict__ outbrev){
  const int dir = blockIdx.y;
  const int b0  = blockIdx.x * RBF;
  const float* Whh = dir ? Whh_b : Whh_f;
  const float* bhh = dir ? bhh_b : bhh_f;
  const float* tab = dir ? tabb  : tabf;
  float* outp = dir ? outbrev : outf;

  __shared__ unsigned short hhi[16*128];   // 4 KB, swizzled
  __shared__ unsigned short hlo[16*128];   // 4 KB
  __shared__ float ghs[G3*17];             // 26 KB, stride 17 = conflict-free
  __shared__ float xts[NBIN*G3];           // 15 KB
  __shared__ int   binr[RBF][L+2];

  const int tid  = threadIdx.x;
  const int wv   = tid >> 6, lane = tid & 63;
  const int l15  = lane & 15, lk = lane >> 4;
  const int gbase = wv * GW;

  // loop-invariant W fragments in registers: 3 M-tiles x 4 K-steps, split hi/lo
  s16x8 whi[3][4], wlo[3][4];
#pragma unroll
  for (int mt = 0; mt < 3; ++mt)
#pragma unroll
    for (int ks = 0; ks < 4; ++ks){
      const float4* s = (const float4*)&Whh[(size_t)(gbase + mt*16 + l15)*D + ks*32 + lk*8];
      split8(s[0], s[1], whi[mt][ks], wlo[mt][ks]);
    }
  for (int i = tid; i < NBIN*G3; i += 512) xts[i] = tab[i];
  for (int i = tid; i < RBF*L; i += 512){
    int r = i / L, t = i % L;
    binr[r][t] = bins[(b0+r)*L + (dir ? (L-1-t) : t)];
  }
  for (int i = tid; i < 16*128; i += 512){ hhi[i] = 0; hlo[i] = 0; }

  const int j  = tid & 127;           // fixed per thread
  const int s0 = tid >> 7;            // sessions s0, s0+4
  const float bh_r = bhh[j], bh_z = bhh[D+j], bh_n = bhh[2*D+j];
  __syncthreads();

  for (int t = 0; t < L; ++t){
    // ---- matmul phase: gh = Whh @ (h_hi + h_lo)
    f32x4 c0 = {0.f,0.f,0.f,0.f}, c1 = c0, c2 = c0;
#pragma unroll
    for (int ks = 0; ks < 4; ++ks){
      int off = l15*256 + ((((ks<<2)+lk) ^ (l15&7)) << 4);
      s16x8 bh8 = *(const s16x8*)((const char*)hhi + off);
      s16x8 bl8 = *(const s16x8*)((const char*)hlo + off);
      c0 = MFMA_B16(whi[0][ks], bh8, c0); c0 = MFMA_B16(whi[0][ks], bl8, c0); c0 = MFMA_B16(wlo[0][ks], bh8, c0);
      c1 = MFMA_B16(whi[1][ks], bh8, c1); c1 = MFMA_B16(whi[1][ks], bl8, c1); c1 = MFMA_B16(wlo[1][ks], bh8, c1);
      c2 = MFMA_B16(whi[2][ks], bh8, c2); c2 = MFMA_B16(whi[2][ks], bl8, c2); c2 = MFMA_B16(wlo[2][ks], bh8, c2);
    }
#pragma unroll
    for (int q = 0; q < 4; ++q){
      ghs[(gbase      + lk*4 + q)*17 + l15] = c0[q];
      ghs[(gbase + 16 + lk*4 + q)*17 + l15] = c1[q];
      ghs[(gbase + 32 + lk*4 + q)*17 + l15] = c2[q];
    }
    __syncthreads();
    // ---- elementwise phase: 2 iters cover sessions s0 and s0+4
#pragma unroll
    for (int it = 0; it < 2; ++it){
      int sess = s0 + it*4;
      int bin  = binr[sess][t];
      const float* xrow = &xts[bin*G3];
      float xr = xrow[j], xz = xrow[D+j], xn = xrow[2*D+j];
      float hr = ghs[j*17+sess]       + bh_r;
      float hz = ghs[(D+j)*17+sess]   + bh_z;
      float hn = ghs[(2*D+j)*17+sess] + bh_n;
      int hb = sess*256 + (((j>>3) ^ (sess&7)) << 4) + (j&7)*2;
      unsigned short uh = *(const unsigned short*)((const char*)hhi + hb);
      unsigned short ul = *(const unsigned short*)((const char*)hlo + hb);
      float hold = __uint_as_float((unsigned)uh<<16) + __uint_as_float((unsigned)ul<<16);
      float rr = sigm(xr+hr), zz = sigm(xz+hz);
      float nn = tanh_fast(xn + rr*hn);
      float hnew = (1.f-zz)*nn + zz*hold;
      unsigned hu, lu; SPLIT1(hnew, hu, lu)
      *(unsigned short*)((char*)hhi + hb) = (unsigned short)hu;
      *(unsigned short*)((char*)hlo + hb) = (unsigned short)lu;
      outp[((size_t)(b0+sess)*L + (dir ? (L-1-t) : t))*D + j] = hnew;
    }
    __syncthreads();
  }
}

// ---------------- e_hat + beta + c (fused) ----------------
__global__ __launch_bounds__(256) void k_beta(
    const float* __restrict__ outf, const float* __restrict__ outbrev,
    const float* __restrict__ htok,
    const float* __restrict__ w1, const float* __restrict__ w2,
    const float* __restrict__ v3,
    const int* __restrict__ seg, const int* __restrict__ pos, int T,
    float* __restrict__ c_pad, int* __restrict__ tokmap){
  __shared__ float w2s[D][2*D+1];     // +1 pad: conflict-free column reads
  __shared__ float w1s[2*D];
  __shared__ float v3s[D];
  __shared__ float hfs[2][D], ehs[2][D];
  __shared__ float redA[4], redB[4];
  for (int i = threadIdx.x; i < D*2*D; i += 256) w2s[i/(2*D)][i%(2*D)] = w2[i];
  for (int i = threadIdx.x; i < 2*D;   i += 256) w1s[i] = w1[i];
  for (int i = threadIdx.x; i < D;     i += 256) v3s[i] = v3[i];
  __syncthreads();
  const int slot = threadIdx.x >> 7;
  const int j    = threadIdx.x & (D-1);
  const int wave = threadIdx.x >> 6;
  const int lane = threadIdx.x & 63;
  for (int t0 = blockIdx.x*2; t0 < T; t0 += gridDim.x*2){
    int t = t0 + slot;
    bool valid = (t < T);
    int sp = 0; float ef = 0.f, eb = 0.f, hfj = 0.f;
    if (valid){
      sp  = seg[t]*L + pos[t];
      ef  = outf[(size_t)sp*D + j];
      eb  = outbrev[(size_t)sp*D + j];
      hfj = htok[(size_t)t*D + j];
    }
    float p = ef*w1s[j] + eb*w1s[D+j];
#pragma unroll
    for (int off = 32; off >= 1; off >>= 1) p += __shfl_down(p, off);
    if (lane == 0) redA[wave] = p;
    __syncthreads();
    float gate = sigm(redA[slot*2] + redA[slot*2+1]);
    float ehj  = gate*ef + (1.f-gate)*eb;
    hfs[slot][j] = hfj;
    ehs[slot][j] = ehj;
    __syncthreads();
    float u = 0.f;
    for (int dd = 0; dd < D; ++dd){
      u += hfs[slot][dd]*w2s[j][dd];
      u += ehs[slot][dd]*w2s[j][D+dd];
    }
    u = tanh_fast(u);
    float pv = u * v3s[j];
#pragma unroll
    for (int off = 32; off >= 1; off >>= 1) pv += __shfl_down(pv, off);
    if (lane == 0) redB[wave] = pv;
    __syncthreads();
    float beta = redB[slot*2] + redB[slot*2+1];
    if (valid){
      c_pad[(size_t)sp*D + j] = beta * hfj;
      if (j == 0) tokmap[sp] = t;
    }
  }
}

// ---------------- z_long ----------------
__global__ void k_zlong(const float* __restrict__ c_pad, float* __restrict__ zl, int Bn){
  int i = blockIdx.x*256 + threadIdx.x;
  if (i >= Bn*D) return;
  int b = i >> 7, j = i & (D-1);
  float s = 0.f;
  for (int l = 0; l < L; ++l) s += c_pad[((size_t)b*L + l)*D + j];
  zl[i] = s;
}

// ---------------- xps[t][g] = dot(c[t], Wih_s[g]) + bih_s[g] ----------------
__global__ __launch_bounds__(G3) void k_xps(
    const float* __restrict__ c_pad, const int* __restrict__ seg,
    const int* __restrict__ pos, const float* __restrict__ Wih,
    const float* __restrict__ bih, int T, float* __restrict__ xps){
  int t0 = blockIdx.x * XT;
  __shared__ float cs[XT][D];
  int nt = min(XT, T - t0);
  for (int i = threadIdx.x; i < XT*D; i += G3){
    int tt = i >> 7, d = i & (D-1);
    float v = 0.f;
    if (tt < nt){
      int t = t0 + tt;
      v = c_pad[(size_t)(seg[t]*L + pos[t])*D + d];
    }
    cs[tt][d] = v;
  }
  __syncthreads();
  int gg = threadIdx.x;
  float acc[XT];
#pragma unroll
  for (int tt = 0; tt < XT; ++tt) acc[tt] = 0.f;
  for (int dc = 0; dc < D; dc += 16){
    float w[16];
#pragma unroll
    for (int k = 0; k < 16; ++k) w[k] = Wih[gg*D + dc + k];
#pragma unroll
    for (int tt = 0; tt < XT; ++tt){
#pragma unroll
      for (int k = 0; k < 16; ++k) acc[tt] += cs[tt][dc+k]*w[k];
    }
  }
  float bi = bih[gg];
  for (int tt = 0; tt < nt; ++tt) xps[(size_t)(t0+tt)*G3 + gg] = acc[tt] + bi;
}

// ---------------- short GRU (MFMA), RBS=4 sessions/block ----------------
__global__ __launch_bounds__(512) void k_grus(
    const float* __restrict__ Whh, const float* __restrict__ bhh,
    const float* __restrict__ bih,
    const float* __restrict__ xps, const int* __restrict__ tokmap,
    float* __restrict__ z_short){
  const int b0 = blockIdx.x * RBS;

  __shared__ unsigned short hhi[16*128];
  __shared__ unsigned short hlo[16*128];
  __shared__ float ghs[G3*17];
  __shared__ int   maprow[RBS][L+2];

  const int tid  = threadIdx.x;
  const int wv   = tid >> 6, lane = tid & 63;
  const int l15  = lane & 15, lk = lane >> 4;
  const int gbase = wv * GW;

  s16x8 whi[3][4], wlo[3][4];
#pragma unroll
  for (int mt = 0; mt < 3; ++mt)
#pragma unroll
    for (int ks = 0; ks < 4; ++ks){
      const float4* s = (const float4*)&Whh[(size_t)(gbase + mt*16 + l15)*D + ks*32 + lk*8];
      split8(s[0], s[1], whi[mt][ks], wlo[mt][ks]);
    }
  for (int i = tid; i < RBS*L; i += 512){
    int r = i / L, t = i % L;
    maprow[r][t] = tokmap[(b0+r)*L + t];
  }
  for (int i = tid; i < 16*128; i += 512){ hhi[i] = 0; hlo[i] = 0; }

  const int j    = tid & 127;
  const int sess = tid >> 7;           // exactly RBS=4 sessions, 1 elementwise iter
  const float bh_r = bhh[j], bh_z = bhh[D+j], bh_n = bhh[2*D+j];
  const float bi_r = bih[j], bi_z = bih[D+j], bi_n = bih[2*D+j];
  const int hb = sess*256 + (((j>>3) ^ (sess&7)) << 4) + (j&7)*2;
  __syncthreads();

  for (int t = 0; t < L; ++t){
    // prefetch xp for this step (independent of h -> hides under MFMA phase)
    int tok = maprow[sess][t];
    float xr = bi_r, xz = bi_z, xn = bi_n;
    if (tok >= 0){
      const float* xrow = &xps[(size_t)tok*G3];
      xr = xrow[j]; xz = xrow[D+j]; xn = xrow[2*D+j];
    }
    // ---- matmul phase
    f32x4 c0 = {0.f,0.f,0.f,0.f}, c1 = c0, c2 = c0;
#pragma unroll
    for (int ks = 0; ks < 4; ++ks){
      int off = l15*256 + ((((ks<<2)+lk) ^ (l15&7)) << 4);
      s16x8 bh8 = *(const s16x8*)((const char*)hhi + off);
      s16x8 bl8 = *(const s16x8*)((const char*)hlo + off);
      c0 = MFMA_B16(whi[0][ks], bh8, c0); c0 = MFMA_B16(whi[0][ks], bl8, c0); c0 = MFMA_B16(wlo[0][ks], bh8, c0);
      c1 = MFMA_B16(whi[1][ks], bh8, c1); c1 = MFMA_B16(whi[1][ks], bl8, c1); c1 = MFMA_B16(wlo[1][ks], bh8, c1);
      c2 = MFMA_B16(whi[2][ks], bh8, c2); c2 = MFMA_B16(whi[2][ks], bl8, c2); c2 = MFMA_B16(wlo[2][ks], bh8, c2);
    }
#pragma unroll
    for (int q = 0; q < 4; ++q){
      ghs[(gbase      + lk*4 + q)*17 + l15] = c0[q];
      ghs[(gbase + 16 + lk*4 + q)*17 + l15] = c1[q];
      ghs[(gbase + 32 + lk*4 + q)*17 + l15] = c2[q];
    }
    __syncthreads();
    // ---- elementwise phase
    {
      float hr = ghs[j*17+sess]       + bh_r;
      float hz = ghs[(D+j)*17+sess]   + bh_z;
      float hn = ghs[(2*D+j)*17+sess] + bh_n;
      unsigned short uh = *(const unsigned short*)((const char*)hhi + hb);
      unsigned short ul = *(const unsigned short*)((const char*)hlo + hb);
      float hold = __uint_as_float((unsigned)uh<<16) + __uint_as_float((unsigned)ul<<16);
      float rr = sigm(xr+hr), zz = sigm(xz+hz);
      float nn = tanh_fast(xn + rr*hn);
      float hnew = (1.f-zz)*nn + zz*hold;
      unsigned hu, lu; SPLIT1(hnew, hu, lu)
      *(unsigned short*)((char*)hhi + hb) = (unsigned short)hu;
      *(unsigned short*)((char*)hlo + hb) = (unsigned short)lu;
    }
    __syncthreads();
  }
  // final hidden -> z_short
  {
    unsigned short uh = *(const unsigned short*)((const char*)hhi + hb);
    unsigned short ul = *(const unsigned short*)((const char*)hlo + hb);
    float hfin = __uint_as_float((unsigned)uh<<16) + __uint_as_float((unsigned)ul<<16);
    z_short[(size_t)(b0+sess)*D + j] = hfin;
  }
}

// ---------------- final scalar gate ----------------
__global__ __launch_bounds__(D) void k_gate(
    const float* __restrict__ zl, const float* __restrict__ zs,
    const float* __restrict__ w3, const float* __restrict__ b3,
    float* __restrict__ zf){
  int b = blockIdx.x;
  int j = threadIdx.x;
  float a = zl[b*D+j], c = zs[b*D+j];
  float p = (a + c) * w3[j];
#pragma unroll
  for (int off = 32; off >= 1; off >>= 1) p += __shfl_down(p, off);
  __shared__ float red[2];
  if ((j & 63) == 0) red[j>>6] = p;
  __syncthreads();
  float f = sigm(red[0] + red[1] + b3[0]);
  zf[b*D+j] = f*a + (1.f-f)*c;
}

// ---------------- out = z_final @ item_emb.T  via split-bf16 MFMA ----------------
__global__ __launch_bounds__(512) void k_fmm(
    const float* __restrict__ zfin, const float* __restrict__ emb,
    float* __restrict__ out, int NI, int Bsz){
  __shared__ unsigned short Ah[BM*KC], Al[BM*KC], Bh[BN*KC], Bl[BN*KC];  // 96 KB

  int nwg = gridDim.x;
  int hw  = blockIdx.x;
  int q = nwg >> 3, r = nwg & 7;
  int xcd = hw & 7, idx = hw >> 3;
  int logical = (xcd < r ? xcd*(q+1) : r*(q+1) + (xcd-r)*q) + idx;
  int ntile = logical >> 2;       // 4 M-tiles per N-tile
  int mtile = logical & 3;
  int m0 = mtile*BM;
  int n0 = ntile*BN;

  const int t    = threadIdx.x;
  const int lane = t & 63;
  const int wid  = t >> 6;
  const int wm   = wid >> 1, wn = wid & 1;   // 4 x 2 wave grid, 64x64 each
  const int l15  = lane & 15, lk = lane >> 4;

  f32x4 acc[4][4];
#pragma unroll
  for (int i = 0; i < 4; ++i)
#pragma unroll
    for (int jj = 0; jj < 4; ++jj){ f32x4 z4 = {0.f,0.f,0.f,0.f}; acc[i][jj] = z4; }

  const int rbase = t >> 3;        // 0..63
  const int c8    = t & 7;         // 8B-slot within 64-col chunk

  for (int kc = 0; kc < 2; ++kc){
#pragma unroll
    for (int p = 0; p < 4; ++p){
      int row = p*64 + rbase;
      int m = m0 + row;
      float4 x0 = make_float4(0.f,0.f,0.f,0.f), x1 = x0;
      if (m < Bsz){
        const float4* src = (const float4*)&zfin[(size_t)m*D + kc*KC + c8*8];
        x0 = src[0]; x1 = src[1];
      }
      s16x8 hv, lv;
      split8(x0, x1, hv, lv);
      int byte = row*128 + ((c8 ^ (row&7))<<4);
      *(s16x8*)((char*)Ah + byte) = hv;
      *(s16x8*)((char*)Al + byte) = lv;
    }
#pragma unroll
    for (int p = 0; p < 2; ++p){
      int row = p*64 + rbase;
      int item = n0 + row;
      float4 x0 = make_float4(0.f,0.f,0.f,0.f), x1 = x0;
      if (item < NI){
        const float4* src = (const float4*)&emb[(size_t)item*D + kc*KC + c8*8];
        x0 = src[0]; x1 = src[1];
      }
      s16x8 hv, lv;
      split8(x0, x1, hv, lv);
      int byte = row*128 + ((c8 ^ (row&7))<<4);
      *(s16x8*)((char*)Bh + byte) = hv;
      *(s16x8*)((char*)Bl + byte) = lv;
    }
    __syncthreads();

#pragma unroll
    for (int ks = 0; ks < 2; ++ks){
      int slotb = ks*4 + lk;
      s16x8 ah[4], al4[4], bh4[4], bl4[4];
#pragma unroll
      for (int mf = 0; mf < 4; ++mf){
        int row = wm*64 + mf*16 + l15;
        int byte = row*128 + ((slotb ^ (row&7))<<4);
        ah[mf]  = *(const s16x8*)((const char*)Ah + byte);
        al4[mf] = *(const s16x8*)((const char*)Al + byte);
      }
#pragma unroll
      for (int nf = 0; nf < 4; ++nf){
        int row = wn*64 + nf*16 + l15;
        int byte = row*128 + ((slotb ^ (row&7))<<4);
        bh4[nf] = *(const s16x8*)((const char*)Bh + byte);
        bl4[nf] = *(const s16x8*)((const char*)Bl + byte);
      }
#pragma unroll
      for (int mf = 0; mf < 4; ++mf)
#pragma unroll
        for (int nf = 0; nf < 4; ++nf){
          acc[mf][nf] = MFMA_B16(ah[mf],  bh4[nf], acc[mf][nf]);
          acc[mf][nf] = MFMA_B16(ah[mf],  bl4[nf], acc[mf][nf]);
          acc[mf][nf] = MFMA_B16(al4[mf], bh4[nf], acc[mf][nf]);
        }
    }
    __syncthreads();
  }

#pragma unroll
  for (int mf = 0; mf < 4; ++mf){
    int rowb = m0 + wm*64 + mf*16 + lk*4;
#pragma unroll
    for (int nf = 0; nf < 4; ++nf){
      int col = n0 + wn*64 + nf*16 + l15;
      if (col < NI){
#pragma unroll
        for (int qq = 0; qq < 4; ++qq){
          int rr = rowb + qq;
          if (rr < Bsz) out[(size_t)rr*NI + col] = acc[mf][nf][qq];
        }
      }
    }
  }
}

extern "C" void kernel_launch(void* const* d_in, const int* in_sizes, int n_in,
                              void* d_out, int out_size, void* d_ws, size_t ws_size,
                              hipStream_t stream){
  const int*   items    = (const int*)d_in[0];
  const int*   edge     = (const int*)d_in[1];
  const float* ew       = (const float*)d_in[2];
  const int*   item2idx = (const int*)d_in[3];
  const int*   bins     = (const int*)d_in[4];
  const int*   seg      = (const int*)d_in[5];
  const int*   pos      = (const int*)d_in[6];
  const float* item_emb = (const float*)d_in[8];
  const float* bin_emb  = (const float*)d_in[9];
  const float* Wih_f = (const float*)d_in[10];
  const float* Whh_f = (const float*)d_in[11];
  const float* bih_f = (const float*)d_in[12];
  const float* bhh_f = (const float*)d_in[13];
  const float* Wih_b = (const float*)d_in[14];
  const float* Whh_b = (const float*)d_in[15];
  const float* bih_b = (const float*)d_in[16];
  const float* bhh_b = (const float*)d_in[17];
  const float* w1    = (const float*)d_in[18];
  const float* w2    = (const float*)d_in[19];
  const float* v3    = (const float*)d_in[20];
  const float* Wih_s = (const float*)d_in[21];
  const float* Whh_s = (const float*)d_in[22];
  const float* bih_s = (const float*)d_in[23];
  const float* bhh_s = (const float*)d_in[24];
  const float* w3    = (const float*)d_in[25];
  const float* b3    = (const float*)d_in[26];
  float* out = (float*)d_out;

  const int NN = in_sizes[0];          // 25500 graph nodes
  const int NE = in_sizes[2];          // 51000 edges
  const int T  = in_sizes[3];          // 25500 tokens
  const int B  = in_sizes[7];          // 1000 sessions
  const int NI = in_sizes[8] / D;      // 100000 items

  const size_t NG  = (size_t)NN * D;
  const size_t BLD = (size_t)B * L * D;

  float* ws   = (float*)d_ws;
  float* accA = ws;
  float* xB   = ws + NG;
  float* xC   = ws + 2*NG;
  float* xps  = ws;                    // reuse A..C later
  float* outf = ws + 3*NG;
  float* outb = outf + BLD;
  float* cpad = outb + BLD;
  int*   tokmap = (int*)(cpad + BLD);
  float* tabf = (float*)(tokmap + (size_t)B*L);
  float* tabb = tabf + NBIN*G3;
  float* zl   = tabb + NBIN*G3;
  float* zs   = zl + (size_t)B*D;
  float* zfin = zs + (size_t)B*D;
  float* htok = xB;                    // token-level h_final after GCN

  // 1) xp tables
  hipLaunchKernelGGL(k_tables, dim3((2*NBIN*G3+255)/256), dim3(256), 0, stream,
                     bin_emb, Wih_f, bih_f, Wih_b, bih_b, tabf, tabb);
  // 2) GCN
  hipLaunchKernelGGL(k_gcn_init, dim3((unsigned)((NG+255)/256)), dim3(256), 0, stream,
                     item_emb, items, accA, xB, (int)NG);
  float* xc = xB; float* xn = xC;
  for (int layer = 0; layer < 3; ++layer){
    hipLaunchKernelGGL(k_zero_f, dim3((unsigned)((NG+255)/256)), dim3(256), 0, stream,
                       xn, (long long)NG);
    hipLaunchKernelGGL(k_scatter, dim3((unsigned)(((size_t)NE*D+255)/256)), dim3(256), 0, stream,
                       xc, xn, edge, edge+NE, ew, NE);
    hipLaunchKernelGGL(k_accum, dim3((unsigned)((NG+255)/256)), dim3(256), 0, stream,
                       accA, xn, (int)NG);
    float* tmp = xc; xc = xn; xn = tmp;
  }
  hipLaunchKernelGGL(k_hgather, dim3((unsigned)(((size_t)T*D+255)/256)), dim3(256), 0, stream,
                     accA, item2idx, htok, T*D);
  // 3) bidirectional GRU (MFMA, W in registers)
  hipLaunchKernelGGL(k_gru_fb, dim3(B/RBF, 2), dim3(512), 0, stream,
                     Whh_f, Whh_b, bhh_f, bhh_b, tabf, tabb, bins, outf, outb);
  // 4) zero padded c + token map
  hipLaunchKernelGGL(k_zero_f, dim3((unsigned)((BLD+255)/256)), dim3(256), 0, stream,
                     cpad, (long long)BLD);
  hipLaunchKernelGGL(k_seti, dim3((B*L+255)/256), dim3(256), 0, stream, tokmap, -1, B*L);
  // 5) fused e_hat/beta/c
  hipLaunchKernelGGL(k_beta, dim3(256), dim3(256), 0, stream,
                     outf, outb, htok, w1, w2, v3, seg, pos, T, cpad, tokmap);
  // 6) z_long
  hipLaunchKernelGGL(k_zlong, dim3((B*D+255)/256), dim3(256), 0, stream, cpad, zl, B);
  // 7) xps for short GRU
  hipLaunchKernelGGL(k_xps, dim3((T+XT-1)/XT), dim3(G3), 0, stream,
                     cpad, seg, pos, Wih_s, bih_s, T, xps);
  // 8) short GRU (MFMA)
  hipLaunchKernelGGL(k_grus, dim3(B/RBS), dim3(512), 0, stream,
                     Whh_s, bhh_s, bih_s, xps, tokmap, zs);
  // 9) scalar gate
  hipLaunchKernelGGL(k_gate, dim3(B), dim3(D), 0, stream, zl, zs, w3, b3, zfin);
  // 10) out = z_final @ item_emb.T  (split-bf16 MFMA GEMM)
  {
    int mtiles = (B + BM - 1)/BM;          // 4
    int ntiles = (NI + BN - 1)/BN;         // 782
    hipLaunchKernelGGL(k_fmm, dim3(mtiles*ntiles), dim3(512), 0, stream,
                       zfin, item_emb, out, NI, B);
  }
}